// Round 3
// baseline (1504.749 us; speedup 1.0000x reference)
//
#include <hip/hip_runtime.h>
#include <hip/hip_bf16.h>

// Problem constants (fixed by setup_inputs)
constexpr int T_ = 4, B_ = 8, N_ = 1024, C_ = 512, H_ = 8, D_ = 64;
constexpr int M_ = B_ * N_;   // 8192 rows per timestep
constexpr int K_ = 512;

#define TAU_INV 0.5f
#define V_TH    1.0f
#define BN_EPS  1e-5f

// ---- load 4 consecutive elements as float ---------------------------------
__device__ __forceinline__ void ld4(const float* p, float* d) {
  const float4 v = *(const float4*)p;
  d[0] = v.x; d[1] = v.y; d[2] = v.z; d[3] = v.w;
}
__device__ __forceinline__ void ld4(const __hip_bfloat16* p, float* d) {
  const ushort4 u = *(const ushort4*)p;
  d[0] = __bfloat162float(*(const __hip_bfloat16*)&u.x);
  d[1] = __bfloat162float(*(const __hip_bfloat16*)&u.y);
  d[2] = __bfloat162float(*(const __hip_bfloat16*)&u.z);
  d[3] = __bfloat162float(*(const __hip_bfloat16*)&u.w);
}
// ---- store 4 consecutive spike values -------------------------------------
__device__ __forceinline__ void st4(__hip_bfloat16* p, const float* s) {
  ushort4 u;
  *(__hip_bfloat16*)&u.x = __float2bfloat16(s[0]);
  *(__hip_bfloat16*)&u.y = __float2bfloat16(s[1]);
  *(__hip_bfloat16*)&u.z = __float2bfloat16(s[2]);
  *(__hip_bfloat16*)&u.w = __float2bfloat16(s[3]);
  *(ushort4*)p = u;
}
__device__ __forceinline__ void st4(float* p, const float* s) {
  *(float4*)p = make_float4(s[0], s[1], s[2], s[3]);
}

// ---------------------------------------------------------------------------
// W transpose: Wt[w][k][d] = W[w][d][k].  Makes per-k rows of W contiguous so
// the GEMM can fetch the B operand with wave-uniform s_load (SGPR broadcast).
// ---------------------------------------------------------------------------
struct WPtrs { const float* W[4]; };

__global__ __launch_bounds__(256) void transpose_w(WPtrs wp, float* __restrict__ Wt)
{
  __shared__ float tile[32][33];
  const int w = blockIdx.z;
  const float* __restrict__ W = wp.W[w];
  float* __restrict__ dst = Wt + (size_t)w * K_ * C_;
  const int k0 = blockIdx.x * 32, d0 = blockIdx.y * 32;
  const int tx = threadIdx.x, ty = threadIdx.y;   // 32 x 8
#pragma unroll
  for (int i = 0; i < 32; i += 8)
    tile[ty + i][tx] = W[(size_t)(d0 + ty + i) * K_ + k0 + tx];
  __syncthreads();
#pragma unroll
  for (int i = 0; i < 32; i += 8)
    dst[(size_t)(k0 + ty + i) * C_ + d0 + tx] = tile[tx][ty + i];
}

// ---------------------------------------------------------------------------
// Fused GEMM (+bias) + BN(eval) + multi-step LIF — SGPR-B design.
// BIT-EXACTNESS CONTRACT: each output's k-summation is a single fp32
// accumulator over k = 0..511 STRICTLY ASCENDING, and the epilogue
// expressions are textually identical to the round-1/2 kernels that matched
// the reference with absmax 0.0. Do not reorder / split k.
//
// Block: 256 threads = 4 waves; tile 64 rows x 128 cols.
// Wave w: all 64 rows (one per lane) x cols [bn0 + w*32, +32).
// A: staged in LDS (row-major, stride 68 floats), read 1 float/lane/kk via
//    ds_read_b128 every 4 kk.
// B: wave-uniform rows of Wt -> scalar loads (SGPR), 1 SGPR operand per FMA.
// ---------------------------------------------------------------------------
template <typename TIn, typename TOut>
__device__ __forceinline__ void gemm_rowlane_body(
    const TIn* __restrict__ X, const float* __restrict__ Wt,
    const float* __restrict__ bias, const float* __restrict__ bnp,
    TOut* __restrict__ S, int bm, int bn0)
{
  constexpr int BK = 64;
  __shared__ __align__(16) float As[64][BK + 4];   // stride 68: conflict-free reads

  const int tid  = threadIdx.x;          // 0..255
  const int lane = tid & 63;
  const int colw = bn0 + __builtin_amdgcn_readfirstlane((tid >> 6) * 32);

  const int srow = tid >> 2;             // staging row 0..63
  const int scol = tid & 3;              // staging quad 0..3

  float mem[32];
#pragma unroll
  for (int j = 0; j < 32; ++j) mem[j] = 0.0f;

  for (int t = 0; t < T_; ++t) {
    const TIn* A = X + (size_t)t * M_ * K_;
    float acc[32];
#pragma unroll
    for (int j = 0; j < 32; ++j) acc[j] = 0.0f;

    for (int k0 = 0; k0 < K_; k0 += BK) {
      // ---- stage A tile (64 rows x BK) , coalesced 64B clusters ----------
#pragma unroll
      for (int i = 0; i < 4; ++i) {
        const int cf = (scol + 4 * i) * 4;      // float col within chunk
        float tmp[4];
        ld4(&A[(size_t)(bm + srow) * K_ + k0 + cf], tmp);
        st4(&As[srow][cf], tmp);
      }
      __syncthreads();

      // ---- hot loop: k strictly ascending --------------------------------
#pragma unroll 4
      for (int kk4 = 0; kk4 < BK / 4; ++kk4) {
        float a4[4];
        ld4(&As[lane][kk4 * 4], a4);
#pragma unroll
        for (int u = 0; u < 4; ++u) {
          const float* __restrict__ wr =
              Wt + (size_t)(k0 + kk4 * 4 + u) * C_ + colw;
          // wave-uniform address -> scalar (SGPR) loads
          float bs[32];
#pragma unroll
          for (int j4 = 0; j4 < 8; ++j4) {
            float tmp[4];
            ld4(wr + j4 * 4, tmp);
            bs[j4 * 4 + 0] = tmp[0]; bs[j4 * 4 + 1] = tmp[1];
            bs[j4 * 4 + 2] = tmp[2]; bs[j4 * 4 + 3] = tmp[3];
          }
          const float av = a4[u];
#pragma unroll
          for (int j = 0; j < 32; ++j)
            acc[j] += av * bs[j];
        }
      }
      __syncthreads();
    }

    // ---- epilogue: bias -> BN -> LIF step t (identical expressions) ------
    const int row = bm + lane;
    TOut* orow = S + ((size_t)t * M_ + row) * C_ + colw;
#pragma unroll
    for (int j4 = 0; j4 < 8; ++j4) {
      float sv[4];
#pragma unroll
      for (int q = 0; q < 4; ++q) {
        const int j = j4 * 4 + q;
        const int d = colw + j;
        const float gg = bnp[d];
        const float be = bnp[C_ + d];
        const float mu = bnp[2 * C_ + d];
        const float inv = 1.0f / sqrtf(bnp[3 * C_ + d] + BN_EPS);
        const float bi = bias[d];
        float y = acc[j] + bi;
        y = (y - mu) * inv * gg + be;
        float m2 = mem[j] + (y - mem[j]) * TAU_INV;
        float s = (m2 - V_TH >= 0.0f) ? 1.0f : 0.0f;
        sv[q] = s;
        mem[j] = (s != 0.0f) ? 0.0f : m2;
      }
      st4(&orow[j4 * 4], sv);
    }
  }
}

struct QKVArgs {
  const float* bias[3];
  const float* bn[3];
  __hip_bfloat16* S[3];
};

// grid (C/128=4, M/64=128, 3)
__global__ __launch_bounds__(256, 4) void qkv_kernel(
    const float* __restrict__ X, const float* __restrict__ Wt, QKVArgs args)
{
  const int w = blockIdx.z;
  gemm_rowlane_body<float, __hip_bfloat16>(
      X, Wt + (size_t)w * K_ * C_, args.bias[w], args.bn[w], args.S[w],
      blockIdx.y * 64, blockIdx.x * 128);
}

// grid (4, 128)
__global__ __launch_bounds__(256, 4) void proj_kernel(
    const __hip_bfloat16* __restrict__ X, const float* __restrict__ Wt,
    const float* __restrict__ bias, const float* __restrict__ bn,
    float* __restrict__ S)
{
  gemm_rowlane_body<__hip_bfloat16, float>(
      X, Wt, bias, bn, S, blockIdx.y * 64, blockIdx.x * 128);
}

// ---------------------------------------------------------------------------
// Linear attention per (t,b,h): kv = k^T v / N (64x64), y = q @ kv (1024x64).
// Spikes are {0,1}: kv entries are counts/1024 and y sums <=64 multiples of
// 2^-10 -> all arithmetic here is EXACT in fp32 regardless of order.
// ---------------------------------------------------------------------------
__global__ __launch_bounds__(256) void attn_kernel(
    const __hip_bfloat16* __restrict__ Q,
    const __hip_bfloat16* __restrict__ Kk,
    const __hip_bfloat16* __restrict__ V,
    float* __restrict__ Y)
{
  __shared__ float s1[64][65];
  __shared__ float s2[64][65];
  __shared__ float kv[64][65];
  const int tid = threadIdx.x;
  const int h = blockIdx.x, b = blockIdx.y, t = blockIdx.z;
  const size_t base = ((size_t)t * B_ + b) * (size_t)N_ * C_ + (size_t)h * D_;
  const int d0 = (tid >> 4) * 4;
  const int e0 = (tid & 15) * 4;

  float acc[4][4];
#pragma unroll
  for (int i = 0; i < 4; ++i)
#pragma unroll
    for (int j = 0; j < 4; ++j) acc[i][j] = 0.0f;

  for (int nc = 0; nc < N_; nc += 64) {
#pragma unroll
    for (int i = 0; i < 16; ++i) {
      int idx = tid + i * 256;
      int r = idx >> 6, c = idx & 63;
      s1[r][c] = __bfloat162float(Kk[base + (size_t)(nc + r) * C_ + c]);
      s2[r][c] = __bfloat162float(V[base + (size_t)(nc + r) * C_ + c]);
    }
    __syncthreads();
#pragma unroll
    for (int nn = 0; nn < 64; ++nn) {
      float a[4], bb[4];
#pragma unroll
      for (int i = 0; i < 4; ++i) a[i] = s1[nn][d0 + i];
#pragma unroll
      for (int j = 0; j < 4; ++j) bb[j] = s2[nn][e0 + j];
#pragma unroll
      for (int i = 0; i < 4; ++i)
#pragma unroll
        for (int j = 0; j < 4; ++j) acc[i][j] += a[i] * bb[j];
    }
    __syncthreads();
  }
#pragma unroll
  for (int i = 0; i < 4; ++i)
#pragma unroll
    for (int j = 0; j < 4; ++j)
      kv[d0 + i][e0 + j] = acc[i][j] * (1.0f / (float)N_);
  __syncthreads();

  for (int rc = 0; rc < N_; rc += 64) {
#pragma unroll
    for (int i = 0; i < 16; ++i) {
      int idx = tid + i * 256;
      int r = idx >> 6, c = idx & 63;
      s1[r][c] = __bfloat162float(Q[base + (size_t)(rc + r) * C_ + c]);
    }
    __syncthreads();
    float o[4][4];
#pragma unroll
    for (int i = 0; i < 4; ++i)
#pragma unroll
      for (int j = 0; j < 4; ++j) o[i][j] = 0.0f;
#pragma unroll
    for (int d = 0; d < 64; ++d) {
      float a[4], bb[4];
#pragma unroll
      for (int i = 0; i < 4; ++i) a[i] = s1[d0 + i][d];
#pragma unroll
      for (int j = 0; j < 4; ++j) bb[j] = kv[d][e0 + j];
#pragma unroll
      for (int i = 0; i < 4; ++i)
#pragma unroll
        for (int j = 0; j < 4; ++j) o[i][j] += a[i] * bb[j];
    }
#pragma unroll
    for (int i = 0; i < 4; ++i)
#pragma unroll
      for (int j = 0; j < 4; ++j)
        Y[base + (size_t)(rc + d0 + i) * C_ + e0 + j] = o[i][j];
    __syncthreads();
  }
}

// ---------------------------------------------------------------------------
// Elementwise multi-step LIF (attn_lif): reads Y (T,M,C) fp32, writes bf16.
// ---------------------------------------------------------------------------
__global__ __launch_bounds__(256) void lif_ew(
    const float* __restrict__ Y, __hip_bfloat16* __restrict__ S,
    size_t npt, int T)
{
  size_t idx = (size_t)blockIdx.x * blockDim.x + threadIdx.x;
  if (idx >= npt) return;
  float mem = 0.0f;
  for (int t = 0; t < T; ++t) {
    float y = Y[(size_t)t * npt + idx];
    mem = mem + (y - mem) * TAU_INV;
    float s = (mem - V_TH >= 0.0f) ? 1.0f : 0.0f;
    S[(size_t)t * npt + idx] = __float2bfloat16(s);
    mem = (s != 0.0f) ? 0.0f : mem;
  }
}

extern "C" void kernel_launch(void* const* d_in, const int* in_sizes, int n_in,
                              void* d_out, int out_size, void* d_ws, size_t ws_size,
                              hipStream_t stream)
{
  const float* x   = (const float*)d_in[0];
  const float* Wq  = (const float*)d_in[1];
  const float* bq  = (const float*)d_in[2];
  const float* Wk  = (const float*)d_in[3];
  const float* bk  = (const float*)d_in[4];
  const float* Wv  = (const float*)d_in[5];
  const float* bv  = (const float*)d_in[6];
  const float* Wp  = (const float*)d_in[7];
  const float* bp  = (const float*)d_in[8];
  const float* bnp = (const float*)d_in[9];   // (4 layers, 4, C)
  float* out = (float*)d_out;

  char* ws = (char*)d_ws;
  const size_t nElem = (size_t)T_ * M_ * C_;   // 16,777,216
  __hip_bfloat16* q_s = (__hip_bfloat16*)ws; ws += nElem * sizeof(__hip_bfloat16);
  __hip_bfloat16* k_s = (__hip_bfloat16*)ws; ws += nElem * sizeof(__hip_bfloat16);
  __hip_bfloat16* v_s = (__hip_bfloat16*)ws; ws += nElem * sizeof(__hip_bfloat16);
  __hip_bfloat16* a_s = (__hip_bfloat16*)ws; ws += nElem * sizeof(__hip_bfloat16);
  float*          Y   = (float*)ws;          ws += nElem * sizeof(float);
  float*          Wt  = (float*)ws;          ws += (size_t)4 * K_ * C_ * sizeof(float);

  // ---- transpose all 4 weight matrices into Wt (k-major) -----------------
  WPtrs wp; wp.W[0] = Wq; wp.W[1] = Wk; wp.W[2] = Wv; wp.W[3] = Wp;
  transpose_w<<<dim3(K_ / 32, C_ / 32, 4), dim3(32, 8), 0, stream>>>(wp, Wt);

  QKVArgs args;
  args.bias[0] = bq; args.bias[1] = bk; args.bias[2] = bv;
  args.bn[0] = bnp + 0 * 4 * C_;
  args.bn[1] = bnp + 1 * 4 * C_;
  args.bn[2] = bnp + 2 * 4 * C_;
  args.S[0] = q_s; args.S[1] = k_s; args.S[2] = v_s;

  qkv_kernel<<<dim3(C_ / 128, M_ / 64, 3), 256, 0, stream>>>(x, Wt, args);

  attn_kernel<<<dim3(H_, B_, T_), 256, 0, stream>>>(q_s, k_s, v_s, Y);

  const size_t npt = (size_t)M_ * C_;          // 4,194,304 per timestep
  lif_ew<<<dim3((unsigned)((npt + 255) / 256)), 256, 0, stream>>>(Y, a_s, npt, T_);

  proj_kernel<<<dim3(C_ / 128, M_ / 64), 256, 0, stream>>>(
      a_s, Wt + (size_t)3 * K_ * C_, bp, bnp + 3 * 4 * C_, out);
}

// Round 4
// 1177.720 us; speedup vs baseline: 1.2777x; 1.2777x over previous
//
#include <hip/hip_runtime.h>
#include <hip/hip_bf16.h>

// Problem constants (fixed by setup_inputs)
constexpr int T_ = 4, B_ = 8, N_ = 1024, C_ = 512, H_ = 8, D_ = 64;
constexpr int M_ = B_ * N_;          // 8192 rows per timestep
constexpr int MT_ = T_ * M_;         // 32768 rows total (t-flattened)
constexpr int K_ = 512;

#define TAU_INV 0.5f
#define V_TH    1.0f
#define BN_EPS  1e-5f

// ---- load 4 consecutive elements as float ---------------------------------
__device__ __forceinline__ void ld4(const float* p, float* d) {
  const float4 v = *(const float4*)p;
  d[0] = v.x; d[1] = v.y; d[2] = v.z; d[3] = v.w;
}
__device__ __forceinline__ void ld4(const __hip_bfloat16* p, float* d) {
  const ushort4 u = *(const ushort4*)p;
  d[0] = __bfloat162float(*(const __hip_bfloat16*)&u.x);
  d[1] = __bfloat162float(*(const __hip_bfloat16*)&u.y);
  d[2] = __bfloat162float(*(const __hip_bfloat16*)&u.z);
  d[3] = __bfloat162float(*(const __hip_bfloat16*)&u.w);
}
// ---- store 4 consecutive values -------------------------------------------
__device__ __forceinline__ void st4(__hip_bfloat16* p, const float* s) {
  ushort4 u;
  *(__hip_bfloat16*)&u.x = __float2bfloat16(s[0]);
  *(__hip_bfloat16*)&u.y = __float2bfloat16(s[1]);
  *(__hip_bfloat16*)&u.z = __float2bfloat16(s[2]);
  *(__hip_bfloat16*)&u.w = __float2bfloat16(s[3]);
  *(ushort4*)p = u;
}
__device__ __forceinline__ void st4(float* p, const float* s) {
  *(float4*)p = make_float4(s[0], s[1], s[2], s[3]);
}

// ---------------------------------------------------------------------------
// GEMM (+bias +BN eval) over all T*M rows at once -> fp32 Y.
// BIT-EXACTNESS CONTRACT: each output's k-summation is a single fp32
// accumulator over k = 0..511 STRICTLY ASCENDING; bias/BN expressions are
// textually identical to the rounds that matched the reference at absmax 0.0.
//
// Tile: 128 rows x 256 cols, 256 threads, 8x16 outputs/thread
// (2 row-groups x 4 col-groups of float4, strided 64).
// A-frag LDS reads are wave-broadcast (address depends only on ty -> 4
// distinct addrs); B-frag reads spread 16 x 16B over all banks (2-way, free).
// Ratio: 96 B LDS per 128 lane-FMAs = 0.75 (R2 was 1.0 and LDS-bound).
// ---------------------------------------------------------------------------
template <typename TIn>
__global__ __launch_bounds__(256, 2) void gemm_bn(
    const TIn* __restrict__ A, const float* __restrict__ W,
    const float* __restrict__ bias, const float* __restrict__ bnp,
    float* __restrict__ Y)
{
  constexpr int BK = 32;
  __shared__ __align__(16) float As[BK][128 + 4];   // row = k; 528B rows (16B-mult)
  __shared__ __align__(16) float Bs[BK][256 + 8];   // 1056B rows (16B-mult)

  const int tid = threadIdx.x;
  const int tx = tid & 15, ty = tid >> 4;
  const int bm = blockIdx.y * 128;
  const int bn0 = blockIdx.x * 256;

  float acc[2][4][4][4];   // [rowgrp g][colgrp h][row i][col j]
#pragma unroll
  for (int g = 0; g < 2; ++g)
#pragma unroll
    for (int h = 0; h < 4; ++h)
#pragma unroll
      for (int i = 0; i < 4; ++i)
#pragma unroll
        for (int j = 0; j < 4; ++j) acc[g][h][i][j] = 0.0f;

  for (int k0 = 0; k0 < K_; k0 += BK) {
    // ---- stage A tile (128 x 32), transposed to k-major -----------------
#pragma unroll
    for (int i = 0; i < 4; ++i) {
      const int idx = tid + 256 * i;          // < 1024 float4s
      const int row = idx >> 3, q = idx & 7;
      float tmp[4];
      ld4(&A[(size_t)(bm + row) * K_ + k0 + q * 4], tmp);
#pragma unroll
      for (int j = 0; j < 4; ++j) As[q * 4 + j][row] = tmp[j];
    }
    // ---- stage B tile (256 x 32 from W row-major), transposed -----------
#pragma unroll
    for (int i = 0; i < 8; ++i) {
      const int idx = tid + 256 * i;          // < 2048 float4s
      const int n = idx >> 3, q = idx & 7;
      float tmp[4];
      ld4(&W[(size_t)(bn0 + n) * K_ + k0 + q * 4], tmp);
#pragma unroll
      for (int j = 0; j < 4; ++j) Bs[q * 4 + j][n] = tmp[j];
    }
    __syncthreads();

    // ---- hot loop: k strictly ascending ---------------------------------
#pragma unroll
    for (int kk = 0; kk < BK; ++kk) {
      float a[2][4], b[4][4];
#pragma unroll
      for (int g = 0; g < 2; ++g)
        ld4(&As[kk][ty * 4 + g * 64], a[g]);
#pragma unroll
      for (int h = 0; h < 4; ++h)
        ld4(&Bs[kk][tx * 4 + h * 64], b[h]);
#pragma unroll
      for (int g = 0; g < 2; ++g)
#pragma unroll
        for (int h = 0; h < 4; ++h)
#pragma unroll
          for (int i = 0; i < 4; ++i)
#pragma unroll
            for (int j = 0; j < 4; ++j)
              acc[g][h][i][j] += a[g][i] * b[h][j];
    }
    __syncthreads();
  }

  // ---- epilogue: bias -> BN (identical expressions), store fp32 y --------
#pragma unroll
  for (int h = 0; h < 4; ++h) {
    const int dl = tx * 4 + h * 64;
    const int d = bn0 + dl;
    float bi[4], gg[4], be[4], mu[4], vv[4];
    ld4(&bias[d], bi);
    ld4(&bnp[d], gg);
    ld4(&bnp[C_ + d], be);
    ld4(&bnp[2 * C_ + d], mu);
    ld4(&bnp[3 * C_ + d], vv);
    float inv[4];
#pragma unroll
    for (int j = 0; j < 4; ++j) inv[j] = 1.0f / sqrtf(vv[j] + BN_EPS);
#pragma unroll
    for (int g = 0; g < 2; ++g)
#pragma unroll
      for (int i = 0; i < 4; ++i) {
        const int row = bm + ty * 4 + g * 64 + i;
        float sv[4];
#pragma unroll
        for (int j = 0; j < 4; ++j) {
          float y = acc[g][h][i][j] + bi[j];
          y = (y - mu[j]) * inv[j] * gg[j] + be[j];
          sv[j] = y;
        }
        st4(&Y[(size_t)row * C_ + d], sv);
      }
  }
}

// ---------------------------------------------------------------------------
// Multi-step LIF scan: Y (T, M*C) fp32 -> spikes (T, M*C).
// Identical update expressions as all prior rounds (absmax 0.0).
// ---------------------------------------------------------------------------
template <typename TOut>
__global__ __launch_bounds__(256) void lif_scan(
    const float* __restrict__ Y, TOut* __restrict__ S)
{
  const size_t npt = (size_t)M_ * C_;
  const size_t idx4 = ((size_t)blockIdx.x * 256 + threadIdx.x) * 4;
  if (idx4 >= npt) return;
  float mem[4] = {0.0f, 0.0f, 0.0f, 0.0f};
#pragma unroll
  for (int t = 0; t < T_; ++t) {
    float y[4], sv[4];
    ld4(&Y[(size_t)t * npt + idx4], y);
#pragma unroll
    for (int j = 0; j < 4; ++j) {
      float m2 = mem[j] + (y[j] - mem[j]) * TAU_INV;
      float s = (m2 - V_TH >= 0.0f) ? 1.0f : 0.0f;
      sv[j] = s;
      mem[j] = (s != 0.0f) ? 0.0f : m2;
    }
    st4(&S[(size_t)t * npt + idx4], sv);
  }
}

// ---------------------------------------------------------------------------
// Linear attention per (t,b,h): kv = k^T v / N (64x64), y = q @ kv (1024x64).
// Spikes are {0,1}: kv entries are counts/1024 and y sums <=64 multiples of
// 2^-10 -> all arithmetic here is EXACT in fp32 regardless of order.
// ---------------------------------------------------------------------------
__global__ __launch_bounds__(256) void attn_kernel(
    const __hip_bfloat16* __restrict__ Q,
    const __hip_bfloat16* __restrict__ Kk,
    const __hip_bfloat16* __restrict__ V,
    float* __restrict__ Y)
{
  __shared__ float s1[64][65];
  __shared__ float s2[64][65];
  __shared__ float kv[64][65];
  const int tid = threadIdx.x;
  const int h = blockIdx.x, b = blockIdx.y, t = blockIdx.z;
  const size_t base = ((size_t)t * B_ + b) * (size_t)N_ * C_ + (size_t)h * D_;
  const int d0 = (tid >> 4) * 4;
  const int e0 = (tid & 15) * 4;

  float acc[4][4];
#pragma unroll
  for (int i = 0; i < 4; ++i)
#pragma unroll
    for (int j = 0; j < 4; ++j) acc[i][j] = 0.0f;

  for (int nc = 0; nc < N_; nc += 64) {
#pragma unroll
    for (int i = 0; i < 16; ++i) {
      int idx = tid + i * 256;
      int r = idx >> 6, c = idx & 63;
      s1[r][c] = __bfloat162float(Kk[base + (size_t)(nc + r) * C_ + c]);
      s2[r][c] = __bfloat162float(V[base + (size_t)(nc + r) * C_ + c]);
    }
    __syncthreads();
#pragma unroll
    for (int nn = 0; nn < 64; ++nn) {
      float a[4], bb[4];
#pragma unroll
      for (int i = 0; i < 4; ++i) a[i] = s1[nn][d0 + i];
#pragma unroll
      for (int j = 0; j < 4; ++j) bb[j] = s2[nn][e0 + j];
#pragma unroll
      for (int i = 0; i < 4; ++i)
#pragma unroll
        for (int j = 0; j < 4; ++j) acc[i][j] += a[i] * bb[j];
    }
    __syncthreads();
  }
#pragma unroll
  for (int i = 0; i < 4; ++i)
#pragma unroll
    for (int j = 0; j < 4; ++j)
      kv[d0 + i][e0 + j] = acc[i][j] * (1.0f / (float)N_);
  __syncthreads();

  for (int rc = 0; rc < N_; rc += 64) {
#pragma unroll
    for (int i = 0; i < 16; ++i) {
      int idx = tid + i * 256;
      int r = idx >> 6, c = idx & 63;
      s1[r][c] = __bfloat162float(Q[base + (size_t)(rc + r) * C_ + c]);
    }
    __syncthreads();
    float o[4][4];
#pragma unroll
    for (int i = 0; i < 4; ++i)
#pragma unroll
      for (int j = 0; j < 4; ++j) o[i][j] = 0.0f;
#pragma unroll
    for (int d = 0; d < 64; ++d) {
      float a[4], bb[4];
#pragma unroll
      for (int i = 0; i < 4; ++i) a[i] = s1[d0 + i][d];
#pragma unroll
      for (int j = 0; j < 4; ++j) bb[j] = kv[d][e0 + j];
#pragma unroll
      for (int i = 0; i < 4; ++i)
#pragma unroll
        for (int j = 0; j < 4; ++j) o[i][j] += a[i] * bb[j];
    }
#pragma unroll
    for (int i = 0; i < 4; ++i)
#pragma unroll
      for (int j = 0; j < 4; ++j)
        Y[base + (size_t)(rc + d0 + i) * C_ + e0 + j] = o[i][j];
    __syncthreads();
  }
}

extern "C" void kernel_launch(void* const* d_in, const int* in_sizes, int n_in,
                              void* d_out, int out_size, void* d_ws, size_t ws_size,
                              hipStream_t stream)
{
  const float* x   = (const float*)d_in[0];
  const float* Wq  = (const float*)d_in[1];
  const float* bq  = (const float*)d_in[2];
  const float* Wk  = (const float*)d_in[3];
  const float* bk  = (const float*)d_in[4];
  const float* Wv  = (const float*)d_in[5];
  const float* bv  = (const float*)d_in[6];
  const float* Wp  = (const float*)d_in[7];
  const float* bp  = (const float*)d_in[8];
  const float* bnp = (const float*)d_in[9];   // (4 layers, 4, C)
  float* out = (float*)d_out;

  char* ws = (char*)d_ws;
  const size_t nElem = (size_t)T_ * M_ * C_;   // 16,777,216
  float*          Y   = (float*)ws;          ws += nElem * sizeof(float);          // 67MB
  __hip_bfloat16* q_s = (__hip_bfloat16*)ws; ws += nElem * sizeof(__hip_bfloat16);
  __hip_bfloat16* k_s = (__hip_bfloat16*)ws; ws += nElem * sizeof(__hip_bfloat16);
  __hip_bfloat16* v_s = (__hip_bfloat16*)ws; ws += nElem * sizeof(__hip_bfloat16);
  __hip_bfloat16* a_s = (__hip_bfloat16*)ws; ws += nElem * sizeof(__hip_bfloat16);

  const dim3 gg(C_ / 256, MT_ / 128);      // (2, 256) = 512 blocks (2/CU)
  const unsigned lif_grid = (unsigned)(((size_t)M_ * C_ / 4 + 255) / 256);

  // q
  gemm_bn<float><<<gg, 256, 0, stream>>>(x, Wq, bq, bnp + 0 * 4 * C_, Y);
  lif_scan<__hip_bfloat16><<<lif_grid, 256, 0, stream>>>(Y, q_s);
  // k
  gemm_bn<float><<<gg, 256, 0, stream>>>(x, Wk, bk, bnp + 1 * 4 * C_, Y);
  lif_scan<__hip_bfloat16><<<lif_grid, 256, 0, stream>>>(Y, k_s);
  // v
  gemm_bn<float><<<gg, 256, 0, stream>>>(x, Wv, bv, bnp + 2 * 4 * C_, Y);
  lif_scan<__hip_bfloat16><<<lif_grid, 256, 0, stream>>>(Y, v_s);

  // attention (exact) -> Y, then attn_lif -> a_s
  attn_kernel<<<dim3(H_, B_, T_), 256, 0, stream>>>(q_s, k_s, v_s, Y);
  lif_scan<__hip_bfloat16><<<lif_grid, 256, 0, stream>>>(Y, a_s);

  // proj -> Y, then proj_lif -> out (fp32 spikes)
  gemm_bn<__hip_bfloat16><<<gg, 256, 0, stream>>>(a_s, Wp, bp, bnp + 3 * 4 * C_, Y);
  lif_scan<float><<<lif_grid, 256, 0, stream>>>(Y, out);
}